// Round 1
// baseline (931.335 us; speedup 1.0000x reference)
//
#include <hip/hip_runtime.h>
#include <math.h>

#define N_NODES 20000
#define E0      320000
#define E_TOT   (E0 + N_NODES)   /* 340000: edges + self-loops */
#define N_GRAPHS 64
#define IN_DIM  39
#define HID     128
#define HEADS   4
#define HHID    (HEADS * HID)    /* 512 */
#define NUM_CONV 3
#define PRED_HID 32
#define NEG_SLOPE 0.2f

__device__ __forceinline__ int esrc(const int* __restrict__ ei, int e) {
    return e < E0 ? ei[e] : (e - E0);
}
__device__ __forceinline__ int edst(const int* __restrict__ ei, int e) {
    return e < E0 ? ei[E0 + e] : (e - E0);
}

// ---------------- CSR build ----------------
__global__ void k_deg(const int* __restrict__ ei, int* __restrict__ deg) {
    int e = blockIdx.x * blockDim.x + threadIdx.x;
    if (e >= E_TOT) return;
    atomicAdd(&deg[edst(ei, e)], 1);
}

// single-block exclusive scan over 20000 degrees
__global__ __launch_bounds__(1024) void k_scan(const int* __restrict__ deg,
                                               int* __restrict__ row_ptr,
                                               int* __restrict__ cursor) {
    __shared__ int part[1024];
    const int CHUNK = 20;  // 1024*20 = 20480 >= 20000
    int t = threadIdx.x;
    int base = t * CHUNK;
    int s = 0;
    for (int i = 0; i < CHUNK; i++) {
        int idx = base + i;
        if (idx < N_NODES) s += deg[idx];
    }
    part[t] = s;
    __syncthreads();
    for (int off = 1; off < 1024; off <<= 1) {
        int v = (t >= off) ? part[t - off] : 0;
        __syncthreads();
        part[t] += v;
        __syncthreads();
    }
    int run = part[t] - s;  // exclusive prefix of this chunk
    for (int i = 0; i < CHUNK; i++) {
        int idx = base + i;
        if (idx < N_NODES) {
            row_ptr[idx] = run;
            cursor[idx]  = run;
            run += deg[idx];
        }
    }
    if (t == 1023) row_ptr[N_NODES] = part[1023];
}

__global__ void k_scatter(const int* __restrict__ ei, int* __restrict__ cursor,
                          int* __restrict__ csr_src, int* __restrict__ csr_eid) {
    int e = blockIdx.x * blockDim.x + threadIdx.x;
    if (e >= E_TOT) return;
    int d = edst(ei, e);
    int pos = atomicAdd(&cursor[d], 1);
    csr_src[pos] = esrc(ei, e);
    csr_eid[pos] = e;
}

// ---------------- embedding: x = nf @ emb_W + emb_b ----------------
__global__ __launch_bounds__(128) void k_emb(const float* __restrict__ nf,
                                             const float* __restrict__ W,
                                             const float* __restrict__ b,
                                             float* __restrict__ x) {
    __shared__ float f[IN_DIM];
    int n = blockIdx.x, t = threadIdx.x;
    if (t < IN_DIM) f[t] = nf[(size_t)n * IN_DIM + t];
    __syncthreads();
    float acc = b[t];
#pragma unroll
    for (int k = 0; k < IN_DIM; k++) acc += f[k] * W[k * HID + t];
    x[(size_t)n * HID + t] = acc;
}

// ---------------- GEMM: H[M,512] = X[M,128] @ W[128,512] ----------------
#define BM 64
#define BN 64
#define LDA 132  /* 132*4B = 528B = 33*16B: keeps float4 alignment, breaks bank stride */
__global__ __launch_bounds__(256) void k_gemm(const float* __restrict__ X,
                                              const float* __restrict__ W,
                                              float* __restrict__ H, int M) {
    __shared__ float As[BM][LDA];
    __shared__ float Bs[HID][BN];
    int bm = blockIdx.x, bn = blockIdx.y;
    int tid = threadIdx.x;
    int row0 = bm * BM;

    // load A tile: 64x128 floats = 2048 float4
#pragma unroll
    for (int i = 0; i < 8; i++) {
        int idx = tid + i * 256;
        int r = idx >> 5;        // 32 float4 per row
        int c4 = idx & 31;
        int gr = row0 + r;
        float4 v = make_float4(0.f, 0.f, 0.f, 0.f);
        if (gr < M) v = *(const float4*)(X + (size_t)gr * HID + c4 * 4);
        *(float4*)(&As[r][c4 * 4]) = v;
    }
    // load B tile: 128x64 floats = 2048 float4
    const float* Wt = W + bn * BN;
#pragma unroll
    for (int i = 0; i < 8; i++) {
        int idx = tid + i * 256;
        int r = idx >> 4;        // 16 float4 per row
        int c4 = idx & 15;
        float4 v = *(const float4*)(Wt + (size_t)r * HHID + c4 * 4);
        *(float4*)(&Bs[r][c4 * 4]) = v;
    }
    __syncthreads();

    int ty = tid >> 4, tx = tid & 15;
    int r0 = ty * 4, c0 = tx * 4;
    float acc[4][4] = {};
#pragma unroll 4
    for (int k = 0; k < HID; k++) {
        float a0 = As[r0 + 0][k], a1 = As[r0 + 1][k];
        float a2 = As[r0 + 2][k], a3 = As[r0 + 3][k];
        float4 bv = *(float4*)(&Bs[k][c0]);
        acc[0][0] += a0 * bv.x; acc[0][1] += a0 * bv.y; acc[0][2] += a0 * bv.z; acc[0][3] += a0 * bv.w;
        acc[1][0] += a1 * bv.x; acc[1][1] += a1 * bv.y; acc[1][2] += a1 * bv.z; acc[1][3] += a1 * bv.w;
        acc[2][0] += a2 * bv.x; acc[2][1] += a2 * bv.y; acc[2][2] += a2 * bv.z; acc[2][3] += a2 * bv.w;
        acc[3][0] += a3 * bv.x; acc[3][1] += a3 * bv.y; acc[3][2] += a3 * bv.z; acc[3][3] += a3 * bv.w;
    }
#pragma unroll
    for (int i = 0; i < 4; i++) {
        int gr = row0 + r0 + i;
        if (gr < M) {
            float4 v = make_float4(acc[i][0], acc[i][1], acc[i][2], acc[i][3]);
            *(float4*)(H + (size_t)gr * HHID + bn * BN + c0) = v;
        }
    }
}

// ---------------- attention dots: a_s/a_d [N, HEADS] ----------------
__global__ __launch_bounds__(64) void k_att(const float* __restrict__ h,
                                            const float* __restrict__ attS,
                                            const float* __restrict__ attD,
                                            float* __restrict__ a_s,
                                            float* __restrict__ a_d) {
    int n = blockIdx.x, t = threadIdx.x;
    const float* hn = h + (size_t)n * HHID;
#pragma unroll
    for (int hd = 0; hd < HEADS; hd++) {
        float h0 = hn[hd * HID + t], h1 = hn[hd * HID + t + 64];
        float s = h0 * attS[hd * HID + t] + h1 * attS[hd * HID + t + 64];
        float d = h0 * attD[hd * HID + t] + h1 * attD[hd * HID + t + 64];
#pragma unroll
        for (int off = 32; off; off >>= 1) {
            s += __shfl_xor(s, off, 64);
            d += __shfl_xor(d, off, 64);
        }
        if (t == 0) { a_s[n * HEADS + hd] = s; a_d[n * HEADS + hd] = d; }
    }
}

// ---------------- per-edge exp + denom ----------------
__global__ void k_edge(const int* __restrict__ ei, const float* __restrict__ a_s,
                       const float* __restrict__ a_d, float* __restrict__ expE,
                       float* __restrict__ denom) {
    int e = blockIdx.x * blockDim.x + threadIdx.x;
    if (e >= E_TOT) return;
    int s = esrc(ei, e), d = edst(ei, e);
#pragma unroll
    for (int hd = 0; hd < HEADS; hd++) {
        float v = a_s[s * HEADS + hd] + a_d[d * HEADS + hd];
        v = v > 0.f ? v : NEG_SLOPE * v;
        float w = expf(v);   // softmax without max-shift: values are O(1), exact alpha
        expE[(size_t)e * HEADS + hd] = w;
        atomicAdd(&denom[d * HEADS + hd], w);
    }
}

// ---------------- aggregation: xout[n,f] = mean_h sum_e alpha*h[src] + b ----------------
__global__ __launch_bounds__(128) void k_aggr(const float* __restrict__ h,
                                              const int* __restrict__ row_ptr,
                                              const int* __restrict__ csr_src,
                                              const int* __restrict__ csr_eid,
                                              const float* __restrict__ expE,
                                              const float* __restrict__ denom,
                                              const float* __restrict__ bias,
                                              float* __restrict__ xout) {
    int n = blockIdx.x, t = threadIdx.x;
    float inv0 = 1.f / denom[n * HEADS + 0];
    float inv1 = 1.f / denom[n * HEADS + 1];
    float inv2 = 1.f / denom[n * HEADS + 2];
    float inv3 = 1.f / denom[n * HEADS + 3];
    float acc0 = 0.f, acc1 = 0.f, acc2 = 0.f, acc3 = 0.f;
    int beg = row_ptr[n], end = row_ptr[n + 1];
    for (int i = beg; i < end; i++) {
        int s = csr_src[i], eid = csr_eid[i];
        const float* ep = expE + (size_t)eid * HEADS;
        float al0 = ep[0] * inv0, al1 = ep[1] * inv1;
        float al2 = ep[2] * inv2, al3 = ep[3] * inv3;
        const float* hp = h + (size_t)s * HHID + t;
        acc0 += al0 * hp[0];
        acc1 += al1 * hp[HID];
        acc2 += al2 * hp[2 * HID];
        acc3 += al3 * hp[3 * HID];
    }
    xout[(size_t)n * HID + t] = 0.25f * (acc0 + acc1 + acc2 + acc3) + bias[t];
}

// ---------------- pooling ----------------
__global__ __launch_bounds__(128) void k_pool(const float* __restrict__ x,
                                              const int* __restrict__ batch,
                                              float* __restrict__ g_sum,
                                              int* __restrict__ g_cnt) {
    int n = blockIdx.x, t = threadIdx.x;
    int b = batch[n];
    atomicAdd(&g_sum[b * HID + t], x[(size_t)n * HID + t]);
    if (t == 0) atomicAdd(&g_cnt[b], 1);
}

// ---------------- head: out[g] = (g_vec @ fcW + fcb) @ outW + outb ----------------
__global__ __launch_bounds__(64) void k_head(const float* __restrict__ g_sum,
                                             const int* __restrict__ g_cnt,
                                             const float* __restrict__ fcW,
                                             const float* __restrict__ fcb,
                                             const float* __restrict__ outW,
                                             const float* __restrict__ outb,
                                             float* __restrict__ out) {
    int g = blockIdx.x, t = threadIdx.x;
    float inv = 1.f / fmaxf((float)g_cnt[g], 1.f);
    float val = 0.f;
    if (t < PRED_HID) {
        float dot = fcb[t];
        for (int f = 0; f < HID; f++)
            dot += (g_sum[g * HID + f] * inv) * fcW[f * PRED_HID + t];
        val = dot * outW[t];
    }
#pragma unroll
    for (int off = 32; off; off >>= 1) val += __shfl_xor(val, off, 64);
    if (t == 0) out[g] = val + outb[0];
}

extern "C" void kernel_launch(void* const* d_in, const int* in_sizes, int n_in,
                              void* d_out, int out_size, void* d_ws, size_t ws_size,
                              hipStream_t stream) {
    const float* node_feat = (const float*)d_in[0];
    const int*   edge_index = (const int*)d_in[1];
    const int*   batch     = (const int*)d_in[2];
    const float* emb_W     = (const float*)d_in[3];
    const float* emb_b     = (const float*)d_in[4];
    const float* lin_W     = (const float*)d_in[5];   // [3][128][512]
    const float* att_src   = (const float*)d_in[6];   // [3][4][128]
    const float* att_dst   = (const float*)d_in[7];
    const float* conv_b    = (const float*)d_in[8];   // [3][128]
    const float* fc_W      = (const float*)d_in[9];
    const float* fc_b      = (const float*)d_in[10];
    const float* out_W     = (const float*)d_in[11];
    const float* out_b     = (const float*)d_in[12];
    float* out = (float*)d_out;

    // workspace carve
    char* p = (char*)d_ws;
    auto alloc = [&](size_t bytes) {
        void* r = (void*)p;
        p += (bytes + 255) & ~(size_t)255;
        return r;
    };
    float* x0      = (float*)alloc((size_t)N_NODES * HID * 4);
    float* x1      = (float*)alloc((size_t)N_NODES * HID * 4);
    float* hbuf    = (float*)alloc((size_t)N_NODES * HHID * 4);
    float* a_s     = (float*)alloc((size_t)N_NODES * HEADS * 4);
    float* a_d     = (float*)alloc((size_t)N_NODES * HEADS * 4);
    float* denom   = (float*)alloc((size_t)N_NODES * HEADS * 4);
    float* expE    = (float*)alloc((size_t)E_TOT * HEADS * 4);
    int*   deg     = (int*)alloc((size_t)(N_NODES + 1) * 4);
    int*   row_ptr = (int*)alloc((size_t)(N_NODES + 1) * 4);
    int*   cursor  = (int*)alloc((size_t)N_NODES * 4);
    int*   csr_src = (int*)alloc((size_t)E_TOT * 4);
    int*   csr_eid = (int*)alloc((size_t)E_TOT * 4);
    float* g_sum   = (float*)alloc((size_t)N_GRAPHS * HID * 4);
    int*   g_cnt   = (int*)alloc((size_t)N_GRAPHS * 4);

    const int EB = (E_TOT + 255) / 256;

    // CSR build (topology shared across layers)
    hipMemsetAsync(deg, 0, (size_t)N_NODES * 4, stream);
    k_deg<<<EB, 256, 0, stream>>>(edge_index, deg);
    k_scan<<<1, 1024, 0, stream>>>(deg, row_ptr, cursor);
    k_scatter<<<EB, 256, 0, stream>>>(edge_index, cursor, csr_src, csr_eid);

    // embedding
    k_emb<<<N_NODES, 128, 0, stream>>>(node_feat, emb_W, emb_b, x0);

    float* xin = x0;
    float* xout = x1;
    for (int l = 0; l < NUM_CONV; l++) {
        const float* Wl  = lin_W + (size_t)l * HID * HHID;
        const float* aSl = att_src + (size_t)l * HEADS * HID;
        const float* aDl = att_dst + (size_t)l * HEADS * HID;
        const float* bl  = conv_b + (size_t)l * HID;

        dim3 gg((N_NODES + BM - 1) / BM, HHID / BN);
        k_gemm<<<gg, 256, 0, stream>>>(xin, Wl, hbuf, N_NODES);
        k_att<<<N_NODES, 64, 0, stream>>>(hbuf, aSl, aDl, a_s, a_d);
        hipMemsetAsync(denom, 0, (size_t)N_NODES * HEADS * 4, stream);
        k_edge<<<EB, 256, 0, stream>>>(edge_index, a_s, a_d, expE, denom);
        k_aggr<<<N_NODES, 128, 0, stream>>>(hbuf, row_ptr, csr_src, csr_eid,
                                            expE, denom, bl, xout);
        float* tmp = xin; xin = xout; xout = tmp;
    }

    // pooling + head
    hipMemsetAsync(g_sum, 0, (size_t)N_GRAPHS * HID * 4, stream);
    hipMemsetAsync(g_cnt, 0, (size_t)N_GRAPHS * 4, stream);
    k_pool<<<N_NODES, 128, 0, stream>>>(xin, batch, g_sum, g_cnt);
    k_head<<<N_GRAPHS, 64, 0, stream>>>(g_sum, g_cnt, fc_W, fc_b,
                                        out_W, out_b, out);
}

// Round 2
// 597.656 us; speedup vs baseline: 1.5583x; 1.5583x over previous
//
#include <hip/hip_runtime.h>
#include <math.h>

#define N_NODES 20000
#define E0      320000
#define E_TOT   (E0 + N_NODES)   /* 340000: edges + self-loops */
#define N_GRAPHS 64
#define IN_DIM  39
#define HID     128
#define HEADS   4
#define HHID    (HEADS * HID)    /* 512 */
#define NUM_CONV 3
#define PRED_HID 32
#define NEG_SLOPE 0.2f

__device__ __forceinline__ int esrc(const int* __restrict__ ei, int e) {
    return e < E0 ? ei[e] : (e - E0);
}
__device__ __forceinline__ int edst(const int* __restrict__ ei, int e) {
    return e < E0 ? ei[E0 + e] : (e - E0);
}

// ---------------- CSR build ----------------
__global__ void k_deg(const int* __restrict__ ei, int* __restrict__ deg) {
    int e = blockIdx.x * blockDim.x + threadIdx.x;
    if (e >= E_TOT) return;
    atomicAdd(&deg[edst(ei, e)], 1);
}

// single-block exclusive scan over 20000 degrees
__global__ __launch_bounds__(1024) void k_scan(const int* __restrict__ deg,
                                               int* __restrict__ row_ptr,
                                               int* __restrict__ cursor) {
    __shared__ int part[1024];
    const int CHUNK = 20;  // 1024*20 = 20480 >= 20000
    int t = threadIdx.x;
    int base = t * CHUNK;
    int s = 0;
    for (int i = 0; i < CHUNK; i++) {
        int idx = base + i;
        if (idx < N_NODES) s += deg[idx];
    }
    part[t] = s;
    __syncthreads();
    for (int off = 1; off < 1024; off <<= 1) {
        int v = (t >= off) ? part[t - off] : 0;
        __syncthreads();
        part[t] += v;
        __syncthreads();
    }
    int run = part[t] - s;  // exclusive prefix of this chunk
    for (int i = 0; i < CHUNK; i++) {
        int idx = base + i;
        if (idx < N_NODES) {
            row_ptr[idx] = run;
            cursor[idx]  = run;
            run += deg[idx];
        }
    }
    if (t == 1023) row_ptr[N_NODES] = part[1023];
}

__global__ void k_scatter(const int* __restrict__ ei, int* __restrict__ cursor,
                          int* __restrict__ csr_src, int* __restrict__ csr_eid) {
    int e = blockIdx.x * blockDim.x + threadIdx.x;
    if (e >= E_TOT) return;
    int d = edst(ei, e);
    int pos = atomicAdd(&cursor[d], 1);
    csr_src[pos] = esrc(ei, e);
    csr_eid[pos] = e;
}

// ---------------- embedding: x = nf @ emb_W + emb_b ----------------
__global__ __launch_bounds__(128) void k_emb(const float* __restrict__ nf,
                                             const float* __restrict__ W,
                                             const float* __restrict__ b,
                                             float* __restrict__ x) {
    __shared__ float f[IN_DIM];
    int n = blockIdx.x, t = threadIdx.x;
    if (t < IN_DIM) f[t] = nf[(size_t)n * IN_DIM + t];
    __syncthreads();
    float acc = b[t];
#pragma unroll
    for (int k = 0; k < IN_DIM; k++) acc += f[k] * W[k * HID + t];
    x[(size_t)n * HID + t] = acc;
}

// ---------------- GEMM: H[M,512] = X[M,128] @ W[128,512] ----------------
#define BM 64
#define BN 64
#define LDA 132  /* keeps float4 alignment, breaks bank stride */
__global__ __launch_bounds__(256) void k_gemm(const float* __restrict__ X,
                                              const float* __restrict__ W,
                                              float* __restrict__ H, int M) {
    __shared__ float As[BM][LDA];
    __shared__ float Bs[HID][BN];
    int bm = blockIdx.x, bn = blockIdx.y;
    int tid = threadIdx.x;
    int row0 = bm * BM;

#pragma unroll
    for (int i = 0; i < 8; i++) {
        int idx = tid + i * 256;
        int r = idx >> 5;        // 32 float4 per row
        int c4 = idx & 31;
        int gr = row0 + r;
        float4 v = make_float4(0.f, 0.f, 0.f, 0.f);
        if (gr < M) v = *(const float4*)(X + (size_t)gr * HID + c4 * 4);
        *(float4*)(&As[r][c4 * 4]) = v;
    }
    const float* Wt = W + bn * BN;
#pragma unroll
    for (int i = 0; i < 8; i++) {
        int idx = tid + i * 256;
        int r = idx >> 4;        // 16 float4 per row
        int c4 = idx & 15;
        float4 v = *(const float4*)(Wt + (size_t)r * HHID + c4 * 4);
        *(float4*)(&Bs[r][c4 * 4]) = v;
    }
    __syncthreads();

    int ty = tid >> 4, tx = tid & 15;
    int r0 = ty * 4, c0 = tx * 4;
    float acc[4][4] = {};
#pragma unroll 4
    for (int k = 0; k < HID; k++) {
        float a0 = As[r0 + 0][k], a1 = As[r0 + 1][k];
        float a2 = As[r0 + 2][k], a3 = As[r0 + 3][k];
        float4 bv = *(float4*)(&Bs[k][c0]);
        acc[0][0] += a0 * bv.x; acc[0][1] += a0 * bv.y; acc[0][2] += a0 * bv.z; acc[0][3] += a0 * bv.w;
        acc[1][0] += a1 * bv.x; acc[1][1] += a1 * bv.y; acc[1][2] += a1 * bv.z; acc[1][3] += a1 * bv.w;
        acc[2][0] += a2 * bv.x; acc[2][1] += a2 * bv.y; acc[2][2] += a2 * bv.z; acc[2][3] += a2 * bv.w;
        acc[3][0] += a3 * bv.x; acc[3][1] += a3 * bv.y; acc[3][2] += a3 * bv.z; acc[3][3] += a3 * bv.w;
    }
#pragma unroll
    for (int i = 0; i < 4; i++) {
        int gr = row0 + r0 + i;
        if (gr < M) {
            float4 v = make_float4(acc[i][0], acc[i][1], acc[i][2], acc[i][3]);
            *(float4*)(H + (size_t)gr * HHID + bn * BN + c0) = v;
        }
    }
}

// ---------------- attention dots: one wave per node ----------------
__global__ __launch_bounds__(256) void k_att(const float* __restrict__ h,
                                             const float* __restrict__ attS,
                                             const float* __restrict__ attD,
                                             float* __restrict__ a_s,
                                             float* __restrict__ a_d) {
    int wid = threadIdx.x >> 6, lane = threadIdx.x & 63;
    int n = blockIdx.x * 4 + wid;
    if (n >= N_NODES) return;
    const float* hn = h + (size_t)n * HHID;
#pragma unroll
    for (int hd = 0; hd < HEADS; hd++) {
        float2 hv  = *(const float2*)(hn + hd * HID + lane * 2);
        float2 as2 = *(const float2*)(attS + hd * HID + lane * 2);
        float2 ad2 = *(const float2*)(attD + hd * HID + lane * 2);
        float s = hv.x * as2.x + hv.y * as2.y;
        float d = hv.x * ad2.x + hv.y * ad2.y;
#pragma unroll
        for (int off = 32; off; off >>= 1) {
            s += __shfl_xor(s, off, 64);
            d += __shfl_xor(d, off, 64);
        }
        if (lane == 0) { a_s[n * HEADS + hd] = s; a_d[n * HEADS + hd] = d; }
    }
}

// ---------------- per-edge exp (no atomics; denom folded into k_aggr) ----------------
__global__ void k_edge(const int* __restrict__ ei, const float* __restrict__ a_s,
                       const float* __restrict__ a_d, float* __restrict__ expE) {
    int e = blockIdx.x * blockDim.x + threadIdx.x;
    if (e >= E_TOT) return;
    int s = esrc(ei, e), d = edst(ei, e);
    float4 vs = *(const float4*)(a_s + (size_t)s * HEADS);
    float4 vd = *(const float4*)(a_d + (size_t)d * HEADS);
    float4 r;
    float v;
    v = vs.x + vd.x; v = v > 0.f ? v : NEG_SLOPE * v; r.x = expf(v);
    v = vs.y + vd.y; v = v > 0.f ? v : NEG_SLOPE * v; r.y = expf(v);
    v = vs.z + vd.z; v = v > 0.f ? v : NEG_SLOPE * v; r.z = expf(v);
    v = vs.w + vd.w; v = v > 0.f ? v : NEG_SLOPE * v; r.w = expf(v);
    *(float4*)(expE + (size_t)e * HEADS) = r;
}

// ---------------- aggregation: denom computed in-loop, no atomics ----------------
__global__ __launch_bounds__(128) void k_aggr(const float* __restrict__ h,
                                              const int* __restrict__ row_ptr,
                                              const int* __restrict__ csr_src,
                                              const int* __restrict__ csr_eid,
                                              const float* __restrict__ expE,
                                              const float* __restrict__ bias,
                                              float* __restrict__ xout) {
    int n = blockIdx.x, t = threadIdx.x;
    float acc0 = 0.f, acc1 = 0.f, acc2 = 0.f, acc3 = 0.f;
    float den0 = 0.f, den1 = 0.f, den2 = 0.f, den3 = 0.f;
    int beg = row_ptr[n], end = row_ptr[n + 1];
    int s_next = 0, e_next = 0;
    if (beg < end) { s_next = csr_src[beg]; e_next = csr_eid[beg]; }
    for (int i = beg; i < end; i++) {
        int s = s_next, eid = e_next;
        if (i + 1 < end) { s_next = csr_src[i + 1]; e_next = csr_eid[i + 1]; }
        float4 ep = *(const float4*)(expE + (size_t)eid * HEADS);
        const float* hp = h + (size_t)s * HHID + t;
        acc0 += ep.x * hp[0];
        acc1 += ep.y * hp[HID];
        acc2 += ep.z * hp[2 * HID];
        acc3 += ep.w * hp[3 * HID];
        den0 += ep.x; den1 += ep.y; den2 += ep.z; den3 += ep.w;
    }
    float r = 0.25f * (acc0 / den0 + acc1 / den1 + acc2 / den2 + acc3 / den3) + bias[t];
    xout[(size_t)n * HID + t] = r;
}

// ---------------- pooling: run-length local reduce (batch sorted) ----------------
#define POOL_NPB 64
__global__ __launch_bounds__(128) void k_pool(const float* __restrict__ x,
                                              const int* __restrict__ batch,
                                              float* __restrict__ g_sum,
                                              int* __restrict__ g_cnt) {
    int t = threadIdx.x;
    int n0 = blockIdx.x * POOL_NPB;
    int n1 = n0 + POOL_NPB; if (n1 > N_NODES) n1 = N_NODES;
    if (n0 >= n1) return;
    int cur = batch[n0];
    float acc = 0.f;
    int cnt = 0;
    for (int n = n0; n < n1; n++) {
        int b = batch[n];            // wave-uniform
        if (b != cur) {
            atomicAdd(&g_sum[cur * HID + t], acc);
            if (t == 0) atomicAdd(&g_cnt[cur], cnt);
            acc = 0.f; cnt = 0; cur = b;
        }
        acc += x[(size_t)n * HID + t];
        cnt++;
    }
    atomicAdd(&g_sum[cur * HID + t], acc);
    if (t == 0) atomicAdd(&g_cnt[cur], cnt);
}

// ---------------- head ----------------
__global__ __launch_bounds__(64) void k_head(const float* __restrict__ g_sum,
                                             const int* __restrict__ g_cnt,
                                             const float* __restrict__ fcW,
                                             const float* __restrict__ fcb,
                                             const float* __restrict__ outW,
                                             const float* __restrict__ outb,
                                             float* __restrict__ out) {
    int g = blockIdx.x, t = threadIdx.x;
    float inv = 1.f / fmaxf((float)g_cnt[g], 1.f);
    float val = 0.f;
    if (t < PRED_HID) {
        float dot = fcb[t];
        for (int f = 0; f < HID; f++)
            dot += (g_sum[g * HID + f] * inv) * fcW[f * PRED_HID + t];
        val = dot * outW[t];
    }
#pragma unroll
    for (int off = 32; off; off >>= 1) val += __shfl_xor(val, off, 64);
    if (t == 0) out[g] = val + outb[0];
}

extern "C" void kernel_launch(void* const* d_in, const int* in_sizes, int n_in,
                              void* d_out, int out_size, void* d_ws, size_t ws_size,
                              hipStream_t stream) {
    const float* node_feat = (const float*)d_in[0];
    const int*   edge_index = (const int*)d_in[1];
    const int*   batch     = (const int*)d_in[2];
    const float* emb_W     = (const float*)d_in[3];
    const float* emb_b     = (const float*)d_in[4];
    const float* lin_W     = (const float*)d_in[5];   // [3][128][512]
    const float* att_src   = (const float*)d_in[6];   // [3][4][128]
    const float* att_dst   = (const float*)d_in[7];
    const float* conv_b    = (const float*)d_in[8];   // [3][128]
    const float* fc_W      = (const float*)d_in[9];
    const float* fc_b      = (const float*)d_in[10];
    const float* out_W     = (const float*)d_in[11];
    const float* out_b     = (const float*)d_in[12];
    float* out = (float*)d_out;

    char* p = (char*)d_ws;
    auto alloc = [&](size_t bytes) {
        void* r = (void*)p;
        p += (bytes + 255) & ~(size_t)255;
        return r;
    };
    float* x0      = (float*)alloc((size_t)N_NODES * HID * 4);
    float* x1      = (float*)alloc((size_t)N_NODES * HID * 4);
    float* hbuf    = (float*)alloc((size_t)N_NODES * HHID * 4);
    float* a_s     = (float*)alloc((size_t)N_NODES * HEADS * 4);
    float* a_d     = (float*)alloc((size_t)N_NODES * HEADS * 4);
    float* expE    = (float*)alloc((size_t)E_TOT * HEADS * 4);
    int*   deg     = (int*)alloc((size_t)(N_NODES + 1) * 4);
    int*   row_ptr = (int*)alloc((size_t)(N_NODES + 1) * 4);
    int*   cursor  = (int*)alloc((size_t)N_NODES * 4);
    int*   csr_src = (int*)alloc((size_t)E_TOT * 4);
    int*   csr_eid = (int*)alloc((size_t)E_TOT * 4);
    float* g_sum   = (float*)alloc((size_t)N_GRAPHS * HID * 4);
    int*   g_cnt   = (int*)alloc((size_t)N_GRAPHS * 4);

    const int EB = (E_TOT + 255) / 256;

    // CSR build (topology shared across layers)
    hipMemsetAsync(deg, 0, (size_t)N_NODES * 4, stream);
    k_deg<<<EB, 256, 0, stream>>>(edge_index, deg);
    k_scan<<<1, 1024, 0, stream>>>(deg, row_ptr, cursor);
    k_scatter<<<EB, 256, 0, stream>>>(edge_index, cursor, csr_src, csr_eid);

    // embedding
    k_emb<<<N_NODES, 128, 0, stream>>>(node_feat, emb_W, emb_b, x0);

    float* xin = x0;
    float* xout = x1;
    for (int l = 0; l < NUM_CONV; l++) {
        const float* Wl  = lin_W + (size_t)l * HID * HHID;
        const float* aSl = att_src + (size_t)l * HEADS * HID;
        const float* aDl = att_dst + (size_t)l * HEADS * HID;
        const float* bl  = conv_b + (size_t)l * HID;

        dim3 gg((N_NODES + BM - 1) / BM, HHID / BN);
        k_gemm<<<gg, 256, 0, stream>>>(xin, Wl, hbuf, N_NODES);
        k_att<<<(N_NODES + 3) / 4, 256, 0, stream>>>(hbuf, aSl, aDl, a_s, a_d);
        k_edge<<<EB, 256, 0, stream>>>(edge_index, a_s, a_d, expE);
        k_aggr<<<N_NODES, 128, 0, stream>>>(hbuf, row_ptr, csr_src, csr_eid,
                                            expE, bl, xout);
        float* tmp = xin; xin = xout; xout = tmp;
    }

    // pooling + head
    hipMemsetAsync(g_sum, 0, (size_t)N_GRAPHS * HID * 4, stream);
    hipMemsetAsync(g_cnt, 0, (size_t)N_GRAPHS * 4, stream);
    k_pool<<<(N_NODES + POOL_NPB - 1) / POOL_NPB, 128, 0, stream>>>(xin, batch, g_sum, g_cnt);
    k_head<<<N_GRAPHS, 64, 0, stream>>>(g_sum, g_cnt, fc_W, fc_b,
                                        out_W, out_b, out);
}